// Round 8
// baseline (774.245 us; speedup 1.0000x reference)
//
#include <hip/hip_runtime.h>

typedef unsigned short u16;
typedef __bf16 bf16x8 __attribute__((ext_vector_type(8)));
typedef float f32x4 __attribute__((ext_vector_type(4)));

#define WSTR 72            // LDS row stride (u16): 64 data + 8 pad
#define TSZ (64 * WSTR)    // one 64-row LDS tile
#define WTSZ (128 * WSTR)  // one 128-row lW tile

__device__ __forceinline__ u16 f2bf(float f) {
    union { float f; unsigned int u; } v; v.f = f;
    unsigned int u = v.u;
    u += 0x7fffu + ((u >> 16) & 1u);   // round-to-nearest-even
    return (u16)(u >> 16);
}

__device__ __forceinline__ u16 cvt_bf(float f) {
    __bf16 h = (__bf16)f;
    union { __bf16 h; u16 u; } v; v.h = h; return v.u;
}

// async global->LDS, 16 B per lane (dest = wave-uniform base + lane*16)
__device__ __forceinline__ void gload16(const u16* g, u16* l) {
    __builtin_amdgcn_global_load_lds((const __attribute__((address_space(1))) unsigned int*)(const void*)g,
                                     (__attribute__((address_space(3))) unsigned int*)(void*)l, 16, 0, 0);
}

#define MFMA16(A, B, C) __builtin_amdgcn_mfma_f32_16x16x32_bf16(A, B, C, 0, 0, 0)

// ---------- 0a) X fp32 -> bf16 ----------
__global__ __launch_bounds__(256) void k_cvtX(const float* __restrict__ src, u16* __restrict__ dst) {
    const size_t i = ((size_t)blockIdx.x * 256 + threadIdx.x) * 8;
    float4 v0 = *(const float4*)(src + i);
    float4 v1 = *(const float4*)(src + i + 4);
    u16 o[8];
    o[0] = f2bf(v0.x); o[1] = f2bf(v0.y); o[2] = f2bf(v0.z); o[3] = f2bf(v0.w);
    o[4] = f2bf(v1.x); o[5] = f2bf(v1.y); o[6] = f2bf(v1.z); o[7] = f2bf(v1.w);
    *(uint4*)(dst + i) = *(const uint4*)o;
}

// ---------- 0b) Wq/Wk/Wv/Wo fp32 -> bf16, stacked [4096][1024] ----------
__global__ __launch_bounds__(256) void k_cvtW(const float* __restrict__ w0, const float* __restrict__ w1,
                                              const float* __restrict__ w2, const float* __restrict__ w3,
                                              u16* __restrict__ dst) {
    const int z = blockIdx.z;
    const float* src = z == 0 ? w0 : z == 1 ? w1 : z == 2 ? w2 : w3;
    const size_t i = ((size_t)blockIdx.x * 256 + threadIdx.x) * 8;
    float4 v0 = *(const float4*)(src + i);
    float4 v1 = *(const float4*)(src + i + 4);
    u16 o[8];
    o[0] = f2bf(v0.x); o[1] = f2bf(v0.y); o[2] = f2bf(v0.z); o[3] = f2bf(v0.w);
    o[4] = f2bf(v1.x); o[5] = f2bf(v1.y); o[6] = f2bf(v1.z); o[7] = f2bf(v1.w);
    *(uint4*)(dst + (size_t)z * 1048576 + i) = *(const uint4*)o;
}

// ---------- 1) merged QKV projection: 128x128 tile, global_load_lds (m97 structure) ----------
__global__ __launch_bounds__(256) void k_qkv(const u16* __restrict__ Xb, const u16* __restrict__ Wb,
                                             const float* __restrict__ bq, const float* __restrict__ bk,
                                             const float* __restrict__ bv,
                                             u16* __restrict__ Q, u16* __restrict__ Kd, u16* __restrict__ Vtmp) {
    __shared__ __align__(16) u16 lA[128 * 32];
    __shared__ __align__(16) u16 lB[128 * 32];
    const int t = threadIdx.x;
    const int n0 = blockIdx.x * 128;
    const int m0 = blockIdx.y * 128;
    const int lane = t & 63, wave = t >> 6;
    const int wm = (wave >> 1) * 64, wn = (wave & 1) * 64;
    const int quad = lane >> 4, m16 = lane & 15;
    const int r4 = t >> 2, c8 = (t & 3) * 8;
    f32x4 acc[4][4] = {};
    for (int k0 = 0; k0 < 1024; k0 += 32) {
        gload16(Xb + (size_t)(m0 + r4) * 1024 + k0 + c8,       &lA[t * 8]);
        gload16(Xb + (size_t)(m0 + 64 + r4) * 1024 + k0 + c8,  &lA[2048 + t * 8]);
        gload16(Wb + (size_t)(n0 + r4) * 1024 + k0 + c8,       &lB[t * 8]);
        gload16(Wb + (size_t)(n0 + 64 + r4) * 1024 + k0 + c8,  &lB[2048 + t * 8]);
        __syncthreads();
        bf16x8 af[4], bfr[4];
#pragma unroll
        for (int i = 0; i < 4; ++i) {
            af[i]  = *(const bf16x8*)(lA + (wm + i * 16 + m16) * 32 + quad * 8);
            bfr[i] = *(const bf16x8*)(lB + (wn + i * 16 + m16) * 32 + quad * 8);
        }
#pragma unroll
        for (int mi = 0; mi < 4; ++mi)
#pragma unroll
            for (int ni = 0; ni < 4; ++ni)
                acc[mi][ni] = MFMA16(af[mi], bfr[ni], acc[mi][ni]);
        __syncthreads();
    }
#pragma unroll
    for (int ni = 0; ni < 4; ++ni) {
        const int gcol = n0 + wn + ni * 16 + m16;      // 0..3071
        const int mat = gcol >> 10;                     // 0=Q 1=K 2=V
        const int col = gcol & 1023;
        const int h = col >> 6, d = col & 63;
        const float bias = (mat == 0 ? bq : mat == 1 ? bk : bv)[col];
        u16* dst = mat == 0 ? Q : mat == 1 ? Kd : Vtmp;
#pragma unroll
        for (int mi = 0; mi < 4; ++mi)
#pragma unroll
            for (int e = 0; e < 4; ++e) {
                const int row = m0 + wm + mi * 16 + quad * 4 + e;
                const int b = row >> 11, l = row & 2047;
                dst[(((size_t)(b * 16 + h)) * 2048 + l) * 64 + d] = cvt_bf(acc[mi][ni][e] + bias);
            }
    }
}

// ---------- 1b) V [bh][l][d] -> V^T [bh][d][l]  (64x64 LDS transpose tiles) ----------
__global__ __launch_bounds__(256) void k_vtr(const u16* __restrict__ Vtmp, u16* __restrict__ Vt) {
    __shared__ __align__(16) u16 ld[64 * WSTR];
    const int t = threadIdx.x;
    const int bh = blockIdx.y;
    const int l0 = blockIdx.x * 64;
    const int r = t >> 3, c8 = (t & 7) * 8;
    const u16* src = Vtmp + (size_t)bh * 2048 * 64 + (size_t)l0 * 64;
    *(uint4*)&ld[r * WSTR + c8]        = *(const uint4*)(src + (size_t)r * 64 + c8);
    *(uint4*)&ld[(r + 32) * WSTR + c8] = *(const uint4*)(src + (size_t)(r + 32) * 64 + c8);
    __syncthreads();
    u16* dst = Vt + (size_t)bh * 64 * 2048 + l0;
#pragma unroll
    for (int half = 0; half < 2; ++half) {
        const int d = r + half * 32;
        u16 p[8];
#pragma unroll
        for (int i = 0; i < 8; ++i) p[i] = ld[(c8 + i) * WSTR + d];
        *(uint4*)(dst + (size_t)d * 2048 + c8) = *(const uint4*)p;
    }
}

// ---------- 2) fused attention, QBLK=128: R7 skeleton, doubled q-tile per block ----------
// 128 q-rows per block, 4 waves: QK^T wave split = 32k x 64q; PV split = 64q x 32d.
// Same sync structure as R7 (proven): 1 __syncthreads per kt, dbuf lK/lV/lW, PV lagged 1 kt.
__global__ __launch_bounds__(256) void k_attn(const u16* __restrict__ Q,
                                              const u16* __restrict__ K,
                                              const u16* __restrict__ Vt,
                                              float* __restrict__ attn,
                                              u16* __restrict__ ctx) {
    __shared__ __align__(16) u16 lK[2 * TSZ];
    __shared__ __align__(16) u16 lV[2 * TSZ];
    __shared__ __align__(16) u16 lW[2 * WTSZ];
    __shared__ float sred[2][128];
    const int t = threadIdx.x;
    const int bh = blockIdx.x;                 // x-fastest: XCD k holds bh = k mod 8 -> K/V L2-resident
    const int m0 = blockIdx.y * 128;
    const int lane = t & 63, wave = t >> 6;
    const int wq = (wave & 1) * 64;            // q-offset: 64 q-rows per wave (4 frags)
    const int wk = (wave >> 1) * 32;           // k-offset (QK^T) and d-offset (PV)
    const int quad = lane >> 4, m16 = lane & 15;
    const int sr = t >> 3, sc = (t & 7) * 8;   // staging: 8 threads per 64-elem row
    const u16* Qh = Q + (size_t)bh * 2048 * 64;
    const u16* Kh = K + (size_t)bh * 2048 * 64;
    const u16* Vh = Vt + (size_t)bh * 64 * 2048;
    float* ah = attn + ((size_t)bh << 22) + (size_t)m0 * 2048;

    const float SC = 0.18033688011112042f;     // 0.125 * log2(e)

    // Q fragments (B-operand): lane holds Q[q=m0+wq+ni*16+m16][d=ks*32+quad*8..+7]
    bf16x8 qf[4][2];
#pragma unroll
    for (int ni = 0; ni < 4; ++ni)
#pragma unroll
        for (int ks = 0; ks < 2; ++ks)
            qf[ni][ks] = *(const bf16x8*)(Qh + (size_t)(m0 + wq + ni * 16 + m16) * 64 + ks * 32 + quad * 8);

    // ---- pass 1: denominators (staged K, dbuf, 1 barrier/kt) ----
    float slane[4] = {0.f, 0.f, 0.f, 0.f};
    {
        *(uint4*)&lK[sr * WSTR + sc]        = *(const uint4*)(Kh + (size_t)sr * 64 + sc);
        *(uint4*)&lK[(sr + 32) * WSTR + sc] = *(const uint4*)(Kh + (size_t)(sr + 32) * 64 + sc);
        int buf = 0;
        for (int kt = 0; kt < 32; ++kt) {
            __syncthreads();
            if (kt < 31) {
                const u16* kp = Kh + (size_t)(kt + 1) * 64 * 64;
                u16* dK = &lK[(buf ^ 1) * TSZ];
                *(uint4*)&dK[sr * WSTR + sc]        = *(const uint4*)(kp + (size_t)sr * 64 + sc);
                *(uint4*)&dK[(sr + 32) * WSTR + sc] = *(const uint4*)(kp + (size_t)(sr + 32) * 64 + sc);
            }
            const u16* lKb = &lK[buf * TSZ];
            f32x4 sacc[2][4] = {};
#pragma unroll
            for (int ks = 0; ks < 2; ++ks) {
                bf16x8 k0 = *(const bf16x8*)(lKb + (wk + m16) * WSTR + ks * 32 + quad * 8);
                bf16x8 k1 = *(const bf16x8*)(lKb + (wk + 16 + m16) * WSTR + ks * 32 + quad * 8);
#pragma unroll
                for (int ni = 0; ni < 4; ++ni) {
                    sacc[0][ni] = MFMA16(k0, qf[ni][ks], sacc[0][ni]);
                    sacc[1][ni] = MFMA16(k1, qf[ni][ks], sacc[1][ni]);
                }
            }
#pragma unroll
            for (int ni = 0; ni < 4; ++ni)
#pragma unroll
                for (int mi = 0; mi < 2; ++mi)
#pragma unroll
                    for (int e = 0; e < 4; ++e)
                        slane[ni] += __builtin_amdgcn_exp2f(sacc[mi][ni][e] * SC);
            buf ^= 1;
        }
    }
#pragma unroll
    for (int ni = 0; ni < 4; ++ni) {
        slane[ni] += __shfl_xor(slane[ni], 16);
        slane[ni] += __shfl_xor(slane[ni], 32);
    }
    if (quad == 0) {
#pragma unroll
        for (int ni = 0; ni < 4; ++ni)
            sred[wave >> 1][wq + ni * 16 + m16] = slane[ni];
    }
    __syncthreads();
    float inv[4];
#pragma unroll
    for (int ni = 0; ni < 4; ++ni) {
        const int q = wq + ni * 16 + m16;
        inv[ni] = 1.0f / (sred[0][q] + sred[1][q]);
    }

    unsigned aoff[2][4], lwoff[2][4];
#pragma unroll
    for (int mi = 0; mi < 2; ++mi)
#pragma unroll
        for (int ni = 0; ni < 4; ++ni) {
            const int q = wq + ni * 16 + m16;
            const int k = wk + mi * 16 + quad * 4;
            aoff[mi][ni]  = (unsigned)(q * 2048 + k);
            lwoff[mi][ni] = (unsigned)(q * WSTR + k);
        }

    // ---- pass 2: weights out + PV (pipelined by one kt) ----
    f32x4 cacc[4][2] = {};
    bf16x8 vp[2][2] = {};
    {
        // prologue: stage K(0), V(0) into buf 0
        *(uint4*)&lK[sr * WSTR + sc]        = *(const uint4*)(Kh + (size_t)sr * 64 + sc);
        *(uint4*)&lK[(sr + 32) * WSTR + sc] = *(const uint4*)(Kh + (size_t)(sr + 32) * 64 + sc);
        *(uint4*)&lV[sr * WSTR + sc]        = *(const uint4*)(Vh + (size_t)sr * 2048 + sc);
        *(uint4*)&lV[(sr + 32) * WSTR + sc] = *(const uint4*)(Vh + (size_t)(sr + 32) * 2048 + sc);
        int buf = 0;
        for (int kt = 0; kt < 32; ++kt) {
            __syncthreads();   // staged(kt) + lW(kt-1) visible; WAR fence for buf^1
            const u16* lKb = &lK[buf * TSZ];
            const u16* lVb = &lV[buf * TSZ];
            // V(kt) fragments (d-rows wk..wk+31) -> registers (consumed at kt+1)
            bf16x8 vn[2][2];
#pragma unroll
            for (int nj = 0; nj < 2; ++nj)
#pragma unroll
                for (int ks = 0; ks < 2; ++ks)
                    vn[nj][ks] = *(const bf16x8*)(lVb + (wk + nj * 16 + m16) * WSTR + ks * 32 + quad * 8);
            // QK^T(kt)
            f32x4 sacc[2][4] = {};
#pragma unroll
            for (int ks = 0; ks < 2; ++ks) {
                bf16x8 k0 = *(const bf16x8*)(lKb + (wk + m16) * WSTR + ks * 32 + quad * 8);
                bf16x8 k1 = *(const bf16x8*)(lKb + (wk + 16 + m16) * WSTR + ks * 32 + quad * 8);
#pragma unroll
                for (int ni = 0; ni < 4; ++ni) {
                    sacc[0][ni] = MFMA16(k0, qf[ni][ks], sacc[0][ni]);
                    sacc[1][ni] = MFMA16(k1, qf[ni][ks], sacc[1][ni]);
                }
            }
            // stage K/V(kt+1) -> buf^1
            if (kt < 31) {
                const u16* kp = Kh + (size_t)(kt + 1) * 64 * 64;
                const u16* vp2 = Vh + (size_t)(kt + 1) * 64;
                u16* dK = &lK[(buf ^ 1) * TSZ];
                u16* dV = &lV[(buf ^ 1) * TSZ];
                *(uint4*)&dK[sr * WSTR + sc]        = *(const uint4*)(kp + (size_t)sr * 64 + sc);
                *(uint4*)&dK[(sr + 32) * WSTR + sc] = *(const uint4*)(kp + (size_t)(sr + 32) * 64 + sc);
                *(uint4*)&dV[sr * WSTR + sc]        = *(const uint4*)(vp2 + (size_t)sr * 2048 + sc);
                *(uint4*)&dV[(sr + 32) * WSTR + sc] = *(const uint4*)(vp2 + (size_t)(sr + 32) * 2048 + sc);
            }
            // w = exp2(s*SC)*inv
#pragma unroll
            for (int mi = 0; mi < 2; ++mi)
#pragma unroll
                for (int ni = 0; ni < 4; ++ni)
#pragma unroll
                    for (int e = 0; e < 4; ++e)
                        sacc[mi][ni][e] = __builtin_amdgcn_exp2f(sacc[mi][ni][e] * SC) * inv[ni];
            // P(kt) -> bf16 -> lW[kt&1]
            u16* lwb = &lW[(kt & 1) * WTSZ];
#pragma unroll
            for (int mi = 0; mi < 2; ++mi)
#pragma unroll
                for (int ni = 0; ni < 4; ++ni) {
                    u16 p[4];
                    p[0] = cvt_bf(sacc[mi][ni][0]); p[1] = cvt_bf(sacc[mi][ni][1]);
                    p[2] = cvt_bf(sacc[mi][ni][2]); p[3] = cvt_bf(sacc[mi][ni][3]);
                    *(uint2*)&lwb[lwoff[mi][ni]] = *(const uint2*)p;
                }
            // final fp32 weights(kt) -> HBM
            float* ap = ah + kt * 64;
#pragma unroll
            for (int mi = 0; mi < 2; ++mi)
#pragma unroll
                for (int ni = 0; ni < 4; ++ni)
                    *(f32x4*)(ap + aoff[mi][ni]) = sacc[mi][ni];
            // PV(kt-1): lW[(kt-1)&1] x V(kt-1) registers
            if (kt > 0) {
                const u16* lwp = &lW[((kt - 1) & 1) * WTSZ];
#pragma unroll
                for (int ks = 0; ks < 2; ++ks)
#pragma unroll
                    for (int mi = 0; mi < 4; ++mi) {
                        bf16x8 a = *(const bf16x8*)(lwp + (wq + mi * 16 + m16) * WSTR + ks * 32 + quad * 8);
                        cacc[mi][0] = MFMA16(a, vp[0][ks], cacc[mi][0]);
                        cacc[mi][1] = MFMA16(a, vp[1][ks], cacc[mi][1]);
                    }
            }
#pragma unroll
            for (int nj = 0; nj < 2; ++nj)
#pragma unroll
                for (int ks = 0; ks < 2; ++ks)
                    vp[nj][ks] = vn[nj][ks];
            buf ^= 1;
        }
        // drain: PV(31)
        __syncthreads();
        const u16* lwp = &lW[(31 & 1) * WTSZ];
#pragma unroll
        for (int ks = 0; ks < 2; ++ks)
#pragma unroll
            for (int mi = 0; mi < 4; ++mi) {
                bf16x8 a = *(const bf16x8*)(lwp + (wq + mi * 16 + m16) * WSTR + ks * 32 + quad * 8);
                cacc[mi][0] = MFMA16(a, vp[0][ks], cacc[mi][0]);
                cacc[mi][1] = MFMA16(a, vp[1][ks], cacc[mi][1]);
            }
    }

    // epilogue: ctx in plain [b*2048+l][1024] row-major (h*64+d cols)
    const int b = bh >> 4, h = bh & 15;
    u16* cp = ctx + ((size_t)b * 2048) * 1024 + h * 64;
#pragma unroll
    for (int mi = 0; mi < 4; ++mi)
#pragma unroll
        for (int nj = 0; nj < 2; ++nj)
#pragma unroll
            for (int e = 0; e < 4; ++e) {
                const int row = m0 + wq + mi * 16 + quad * 4 + e;
                const int col = wk + nj * 16 + m16;
                cp[(size_t)row * 1024 + col] = cvt_bf(cacc[mi][nj][e]);
            }
}

// ---------- 3) out = ctx @ Wo^T + bo, m97 128x128 structure; ctx is [4096][1024] bf16 ----------
__global__ __launch_bounds__(256) void k_out(const u16* __restrict__ ctx,
                                             const u16* __restrict__ WoB,
                                             const float* __restrict__ bo,
                                             float* __restrict__ out) {
    __shared__ __align__(16) u16 lA[128 * 32];
    __shared__ __align__(16) u16 lB[128 * 32];
    const int t = threadIdx.x;
    const int n0 = blockIdx.x * 128;
    const int m0 = blockIdx.y * 128;
    const int lane = t & 63, wave = t >> 6;
    const int wm = (wave >> 1) * 64, wn = (wave & 1) * 64;
    const int quad = lane >> 4, m16 = lane & 15;
    const int r4 = t >> 2, c8 = (t & 3) * 8;
    f32x4 acc[4][4] = {};
    for (int k0 = 0; k0 < 1024; k0 += 32) {
        gload16(ctx + (size_t)(m0 + r4) * 1024 + k0 + c8,       &lA[t * 8]);
        gload16(ctx + (size_t)(m0 + 64 + r4) * 1024 + k0 + c8,  &lA[2048 + t * 8]);
        gload16(WoB + (size_t)(n0 + r4) * 1024 + k0 + c8,       &lB[t * 8]);
        gload16(WoB + (size_t)(n0 + 64 + r4) * 1024 + k0 + c8,  &lB[2048 + t * 8]);
        __syncthreads();
        bf16x8 af[4], bfr[4];
#pragma unroll
        for (int i = 0; i < 4; ++i) {
            af[i]  = *(const bf16x8*)(lA + (wm + i * 16 + m16) * 32 + quad * 8);
            bfr[i] = *(const bf16x8*)(lB + (wn + i * 16 + m16) * 32 + quad * 8);
        }
#pragma unroll
        for (int mi = 0; mi < 4; ++mi)
#pragma unroll
            for (int ni = 0; ni < 4; ++ni)
                acc[mi][ni] = MFMA16(af[mi], bfr[ni], acc[mi][ni]);
        __syncthreads();
    }
#pragma unroll
    for (int ni = 0; ni < 4; ++ni) {
        const int col = n0 + wn + ni * 16 + m16;
        const float bv = bo[col];
#pragma unroll
        for (int mi = 0; mi < 4; ++mi)
#pragma unroll
            for (int e = 0; e < 4; ++e) {
                const int row = m0 + wm + mi * 16 + quad * 4 + e;
                out[(size_t)row * 1024 + col] = acc[mi][ni][e] + bv;
            }
    }
}

extern "C" void kernel_launch(void* const* d_in, const int* in_sizes, int n_in,
                              void* d_out, int out_size, void* d_ws, size_t ws_size,
                              hipStream_t stream) {
    const float* x  = (const float*)d_in[0];
    const float* Wq = (const float*)d_in[1];
    const float* bq = (const float*)d_in[2];
    const float* Wk = (const float*)d_in[3];
    const float* bk = (const float*)d_in[4];
    const float* Wv = (const float*)d_in[5];
    const float* bv = (const float*)d_in[6];
    const float* Wo = (const float*)d_in[7];
    const float* bo = (const float*)d_in[8];

    float* out_f = (float*)d_out;
    float* attn  = out_f + (size_t)4096 * 1024;  // [2,16,2048,2048]

    u16* Xb = (u16*)d_ws;                        // X bf16 [4096][1024]; reused as ctx after k_qkv
    u16* Wb = Xb + (size_t)4194304;              // Wq|Wk|Wv|Wo bf16 stacked [4096][1024]
    u16* Qb = Wb + (size_t)4194304;
    u16* Kb = Qb + (size_t)4194304;
    u16* Vt = Kb + (size_t)4194304;              // V transposed [b,h,d,l]
    u16* Vtmp = (u16*)attn;                      // V [bh][l][d] scratch inside attn region (dead until k_attn)

    dim3 blk(256);
    k_cvtX<<<dim3(2048), blk, 0, stream>>>(x, Xb);
    k_cvtW<<<dim3(512, 1, 4), blk, 0, stream>>>(Wq, Wk, Wv, Wo, Wb);
    k_qkv<<<dim3(24, 32), blk, 0, stream>>>(Xb, Wb, bq, bk, bv, Qb, Kb, Vtmp);
    k_vtr<<<dim3(32, 32), blk, 0, stream>>>(Vtmp, Vt);
    k_attn<<<dim3(32, 16), blk, 0, stream>>>(Qb, Kb, Vt, attn, Xb);  // ctx -> Xb; QBLK=128
    k_out<<<dim3(8, 32), blk, 0, stream>>>(Xb, Wb + (size_t)3072 * 1024, bo, out_f);
}

// Round 9
// 693.561 us; speedup vs baseline: 1.1163x; 1.1163x over previous
//
#include <hip/hip_runtime.h>

typedef unsigned short u16;
typedef __bf16 bf16x8 __attribute__((ext_vector_type(8)));
typedef float f32x4 __attribute__((ext_vector_type(4)));

#define WSTR 72            // LDS row stride (u16): 64 data + 8 pad
#define TSZ (64 * WSTR)    // one 64-row LDS tile

__device__ __forceinline__ u16 f2bf(float f) {
    union { float f; unsigned int u; } v; v.f = f;
    unsigned int u = v.u;
    u += 0x7fffu + ((u >> 16) & 1u);   // round-to-nearest-even
    return (u16)(u >> 16);
}

__device__ __forceinline__ u16 cvt_bf(float f) {
    __bf16 h = (__bf16)f;
    union { __bf16 h; u16 u; } v; v.h = h; return v.u;
}

// async global->LDS, 16 B per lane (dest = wave-uniform base + lane*16)
__device__ __forceinline__ void gload16(const u16* g, u16* l) {
    __builtin_amdgcn_global_load_lds((const __attribute__((address_space(1))) unsigned int*)(const void*)g,
                                     (__attribute__((address_space(3))) unsigned int*)(void*)l, 16, 0, 0);
}

#define MFMA16(A, B, C) __builtin_amdgcn_mfma_f32_16x16x32_bf16(A, B, C, 0, 0, 0)

// lgkm-only barrier: LDS ops drained, vmem (weight stores, staged loads) stays in flight.
// Single opaque asm so nothing is scheduled between the wait and the barrier (R5 form).
#define LGKM_BARRIER() do { \
    asm volatile("s_waitcnt lgkmcnt(0)\n\ts_barrier" ::: "memory"); \
    __builtin_amdgcn_sched_barrier(0); \
} while (0)

// ---------- 0a) X fp32 -> bf16 ----------
__global__ __launch_bounds__(256) void k_cvtX(const float* __restrict__ src, u16* __restrict__ dst) {
    const size_t i = ((size_t)blockIdx.x * 256 + threadIdx.x) * 8;
    float4 v0 = *(const float4*)(src + i);
    float4 v1 = *(const float4*)(src + i + 4);
    u16 o[8];
    o[0] = f2bf(v0.x); o[1] = f2bf(v0.y); o[2] = f2bf(v0.z); o[3] = f2bf(v0.w);
    o[4] = f2bf(v1.x); o[5] = f2bf(v1.y); o[6] = f2bf(v1.z); o[7] = f2bf(v1.w);
    *(uint4*)(dst + i) = *(const uint4*)o;
}

// ---------- 0b) Wq/Wk/Wv/Wo fp32 -> bf16, stacked [4096][1024] ----------
__global__ __launch_bounds__(256) void k_cvtW(const float* __restrict__ w0, const float* __restrict__ w1,
                                              const float* __restrict__ w2, const float* __restrict__ w3,
                                              u16* __restrict__ dst) {
    const int z = blockIdx.z;
    const float* src = z == 0 ? w0 : z == 1 ? w1 : z == 2 ? w2 : w3;
    const size_t i = ((size_t)blockIdx.x * 256 + threadIdx.x) * 8;
    float4 v0 = *(const float4*)(src + i);
    float4 v1 = *(const float4*)(src + i + 4);
    u16 o[8];
    o[0] = f2bf(v0.x); o[1] = f2bf(v0.y); o[2] = f2bf(v0.z); o[3] = f2bf(v0.w);
    o[4] = f2bf(v1.x); o[5] = f2bf(v1.y); o[6] = f2bf(v1.z); o[7] = f2bf(v1.w);
    *(uint4*)(dst + (size_t)z * 1048576 + i) = *(const uint4*)o;
}

// ---------- 1) merged QKV projection: 128x128 tile, global_load_lds (m97 structure) ----------
__global__ __launch_bounds__(256) void k_qkv(const u16* __restrict__ Xb, const u16* __restrict__ Wb,
                                             const float* __restrict__ bq, const float* __restrict__ bk,
                                             const float* __restrict__ bv,
                                             u16* __restrict__ Q, u16* __restrict__ Kd, u16* __restrict__ Vtmp) {
    __shared__ __align__(16) u16 lA[128 * 32];
    __shared__ __align__(16) u16 lB[128 * 32];
    const int t = threadIdx.x;
    const int n0 = blockIdx.x * 128;
    const int m0 = blockIdx.y * 128;
    const int lane = t & 63, wave = t >> 6;
    const int wm = (wave >> 1) * 64, wn = (wave & 1) * 64;
    const int quad = lane >> 4, m16 = lane & 15;
    const int r4 = t >> 2, c8 = (t & 3) * 8;
    f32x4 acc[4][4] = {};
    for (int k0 = 0; k0 < 1024; k0 += 32) {
        gload16(Xb + (size_t)(m0 + r4) * 1024 + k0 + c8,       &lA[t * 8]);
        gload16(Xb + (size_t)(m0 + 64 + r4) * 1024 + k0 + c8,  &lA[2048 + t * 8]);
        gload16(Wb + (size_t)(n0 + r4) * 1024 + k0 + c8,       &lB[t * 8]);
        gload16(Wb + (size_t)(n0 + 64 + r4) * 1024 + k0 + c8,  &lB[2048 + t * 8]);
        __syncthreads();
        bf16x8 af[4], bfr[4];
#pragma unroll
        for (int i = 0; i < 4; ++i) {
            af[i]  = *(const bf16x8*)(lA + (wm + i * 16 + m16) * 32 + quad * 8);
            bfr[i] = *(const bf16x8*)(lB + (wn + i * 16 + m16) * 32 + quad * 8);
        }
#pragma unroll
        for (int mi = 0; mi < 4; ++mi)
#pragma unroll
            for (int ni = 0; ni < 4; ++ni)
                acc[mi][ni] = MFMA16(af[mi], bfr[ni], acc[mi][ni]);
        __syncthreads();
    }
#pragma unroll
    for (int ni = 0; ni < 4; ++ni) {
        const int gcol = n0 + wn + ni * 16 + m16;      // 0..3071
        const int mat = gcol >> 10;                     // 0=Q 1=K 2=V
        const int col = gcol & 1023;
        const int h = col >> 6, d = col & 63;
        const float bias = (mat == 0 ? bq : mat == 1 ? bk : bv)[col];
        u16* dst = mat == 0 ? Q : mat == 1 ? Kd : Vtmp;
#pragma unroll
        for (int mi = 0; mi < 4; ++mi)
#pragma unroll
            for (int e = 0; e < 4; ++e) {
                const int row = m0 + wm + mi * 16 + quad * 4 + e;
                const int b = row >> 11, l = row & 2047;
                dst[(((size_t)(b * 16 + h)) * 2048 + l) * 64 + d] = cvt_bf(acc[mi][ni][e] + bias);
            }
    }
}

// ---------- 1b) V [bh][l][d] -> V^T [bh][d][l]  (64x64 LDS transpose tiles) ----------
__global__ __launch_bounds__(256) void k_vtr(const u16* __restrict__ Vtmp, u16* __restrict__ Vt) {
    __shared__ __align__(16) u16 ld[64 * WSTR];
    const int t = threadIdx.x;
    const int bh = blockIdx.y;
    const int l0 = blockIdx.x * 64;
    const int r = t >> 3, c8 = (t & 7) * 8;
    const u16* src = Vtmp + (size_t)bh * 2048 * 64 + (size_t)l0 * 64;
    *(uint4*)&ld[r * WSTR + c8]        = *(const uint4*)(src + (size_t)r * 64 + c8);
    *(uint4*)&ld[(r + 32) * WSTR + c8] = *(const uint4*)(src + (size_t)(r + 32) * 64 + c8);
    __syncthreads();
    u16* dst = Vt + (size_t)bh * 64 * 2048 + l0;
#pragma unroll
    for (int half = 0; half < 2; ++half) {
        const int d = r + half * 32;
        u16 p[8];
#pragma unroll
        for (int i = 0; i < 8; ++i) p[i] = ld[(c8 + i) * WSTR + d];
        *(uint4*)(dst + (size_t)d * 2048 + c8) = *(const uint4*)p;
    }
}

// ---------- 2) fused attention: R7 geometry + T14 reg-staging split + lgkm-only barriers ----------
// 64 q-rows/block, 4 waves. One barrier per kt. Staging loads issued right after the barrier,
// ds_written at iteration end (latency hidden under QK^T/exp). Weight stores never drained
// at barriers (lgkm-only). PV lagged one kt via dbuf lW.
__global__ __launch_bounds__(256) void k_attn(const u16* __restrict__ Q,
                                              const u16* __restrict__ K,
                                              const u16* __restrict__ Vt,
                                              float* __restrict__ attn,
                                              u16* __restrict__ ctx) {
    __shared__ __align__(16) u16 lK[2 * TSZ];
    __shared__ __align__(16) u16 lV[2 * TSZ];
    __shared__ __align__(16) u16 lW[2 * TSZ];
    __shared__ float sred[2][64];
    const int t = threadIdx.x;
    const int bh = blockIdx.x;                 // x-fastest: XCD k holds bh = k mod 8 -> K/V L2-resident
    const int m0 = blockIdx.y * 64;
    const int lane = t & 63, wave = t >> 6;
    const int wq = (wave & 1) * 32;            // q-offset (QK^T N axis)
    const int wk = (wave >> 1) * 32;           // k-offset (QK^T M axis)
    const int wm = (wave >> 1) * 32, wn = (wave & 1) * 32;  // PV split
    const int quad = lane >> 4, m16 = lane & 15;
    const int sr = t >> 3, sc = (t & 7) * 8;   // staging: 8 threads per 64-elem row
    const u16* Qh = Q + (size_t)bh * 2048 * 64;
    const u16* Kh = K + (size_t)bh * 2048 * 64;
    const u16* Vh = Vt + (size_t)bh * 64 * 2048;
    float* ah = attn + ((size_t)bh << 22) + (size_t)m0 * 2048;

    const float SC = 0.18033688011112042f;     // 0.125 * log2(e)

    // Q fragments (B-operand): lane holds Q[q=m0+wq+ni*16+m16][d=ks*32+quad*8..+7]
    bf16x8 qf[2][2];
#pragma unroll
    for (int ni = 0; ni < 2; ++ni)
#pragma unroll
        for (int ks = 0; ks < 2; ++ks)
            qf[ni][ks] = *(const bf16x8*)(Qh + (size_t)(m0 + wq + ni * 16 + m16) * 64 + ks * 32 + quad * 8);

    // ---- pass 1: denominators (staged K, dbuf, 1 lgkm-barrier/kt, T14 reg staging) ----
    float slane[2] = {0.f, 0.f};
    {
        *(uint4*)&lK[sr * WSTR + sc]        = *(const uint4*)(Kh + (size_t)sr * 64 + sc);
        *(uint4*)&lK[(sr + 32) * WSTR + sc] = *(const uint4*)(Kh + (size_t)(sr + 32) * 64 + sc);
        int buf = 0;
        for (int kt = 0; kt < 32; ++kt) {
            LGKM_BARRIER();
            // T14: issue next-tile loads NOW, write to LDS at iteration end
            uint4 kr0, kr1;
            if (kt < 31) {
                const u16* kp = Kh + (size_t)(kt + 1) * 64 * 64;
                kr0 = *(const uint4*)(kp + (size_t)sr * 64 + sc);
                kr1 = *(const uint4*)(kp + (size_t)(sr + 32) * 64 + sc);
            }
            const u16* lKb = &lK[buf * TSZ];
            bf16x8 k00 = *(const bf16x8*)(lKb + (wk + m16) * WSTR + quad * 8);
            bf16x8 k01 = *(const bf16x8*)(lKb + (wk + m16) * WSTR + 32 + quad * 8);
            bf16x8 k10 = *(const bf16x8*)(lKb + (wk + 16 + m16) * WSTR + quad * 8);
            bf16x8 k11 = *(const bf16x8*)(lKb + (wk + 16 + m16) * WSTR + 32 + quad * 8);
            f32x4 sacc[2][2] = {};
            sacc[0][0] = MFMA16(k00, qf[0][0], sacc[0][0]);
            sacc[0][1] = MFMA16(k00, qf[1][0], sacc[0][1]);
            sacc[1][0] = MFMA16(k10, qf[0][0], sacc[1][0]);
            sacc[1][1] = MFMA16(k10, qf[1][0], sacc[1][1]);
            sacc[0][0] = MFMA16(k01, qf[0][1], sacc[0][0]);
            sacc[0][1] = MFMA16(k01, qf[1][1], sacc[0][1]);
            sacc[1][0] = MFMA16(k11, qf[0][1], sacc[1][0]);
            sacc[1][1] = MFMA16(k11, qf[1][1], sacc[1][1]);
#pragma unroll
            for (int mi = 0; mi < 2; ++mi)
#pragma unroll
                for (int e = 0; e < 4; ++e) {
                    slane[0] += __builtin_amdgcn_exp2f(sacc[mi][0][e] * SC);
                    slane[1] += __builtin_amdgcn_exp2f(sacc[mi][1][e] * SC);
                }
            if (kt < 31) {
                u16* dK = &lK[(buf ^ 1) * TSZ];
                *(uint4*)&dK[sr * WSTR + sc]        = kr0;
                *(uint4*)&dK[(sr + 32) * WSTR + sc] = kr1;
            }
            buf ^= 1;
        }
    }
#pragma unroll
    for (int ni = 0; ni < 2; ++ni) {
        slane[ni] += __shfl_xor(slane[ni], 16);
        slane[ni] += __shfl_xor(slane[ni], 32);
    }
    __syncthreads();   // full drain between passes (also covers pass-1 tail reads before re-staging)
    if (quad == 0) {
        sred[wave >> 1][wq + m16]      = slane[0];
        sred[wave >> 1][wq + 16 + m16] = slane[1];
    }
    __syncthreads();
    float inv[2];
    inv[0] = 1.0f / (sred[0][wq + m16]      + sred[1][wq + m16]);
    inv[1] = 1.0f / (sred[0][wq + 16 + m16] + sred[1][wq + 16 + m16]);

    unsigned aoff[2][2], lwoff[2][2];
#pragma unroll
    for (int mi = 0; mi < 2; ++mi)
#pragma unroll
        for (int ni = 0; ni < 2; ++ni) {
            const int q = wq + ni * 16 + m16;
            const int k = wk + mi * 16 + quad * 4;
            aoff[mi][ni]  = (unsigned)(q * 2048 + k);
            lwoff[mi][ni] = (unsigned)(q * WSTR + k);
        }

    // ---- pass 2: weights out + PV (pipelined by one kt, T14 staging, lgkm barriers) ----
    f32x4 cacc[2][2] = {};
    bf16x8 vp00 = {}, vp01 = {}, vp10 = {}, vp11 = {};
    {
        // prologue: stage K(0), V(0) into buf 0
        *(uint4*)&lK[sr * WSTR + sc]        = *(const uint4*)(Kh + (size_t)sr * 64 + sc);
        *(uint4*)&lK[(sr + 32) * WSTR + sc] = *(const uint4*)(Kh + (size_t)(sr + 32) * 64 + sc);
        *(uint4*)&lV[sr * WSTR + sc]        = *(const uint4*)(Vh + (size_t)sr * 2048 + sc);
        *(uint4*)&lV[(sr + 32) * WSTR + sc] = *(const uint4*)(Vh + (size_t)(sr + 32) * 2048 + sc);
        int buf = 0;
        for (int kt = 0; kt < 32; ++kt) {
            LGKM_BARRIER();   // staged(kt) + lW(kt-1) visible; vmem stays in flight
            // T14: issue next-tile loads NOW
            uint4 kr0, kr1, vr0, vr1;
            if (kt < 31) {
                const u16* kp  = Kh + (size_t)(kt + 1) * 64 * 64;
                const u16* vp2 = Vh + (size_t)(kt + 1) * 64;
                kr0 = *(const uint4*)(kp + (size_t)sr * 64 + sc);
                kr1 = *(const uint4*)(kp + (size_t)(sr + 32) * 64 + sc);
                vr0 = *(const uint4*)(vp2 + (size_t)sr * 2048 + sc);
                vr1 = *(const uint4*)(vp2 + (size_t)(sr + 32) * 2048 + sc);
            }
            const u16* lKb = &lK[buf * TSZ];
            const u16* lVb = &lV[buf * TSZ];
            // V(kt) fragments -> registers (consumed by PV at kt+1)
            bf16x8 vn00 = *(const bf16x8*)(lVb + (wn + m16) * WSTR + quad * 8);
            bf16x8 vn01 = *(const bf16x8*)(lVb + (wn + m16) * WSTR + 32 + quad * 8);
            bf16x8 vn10 = *(const bf16x8*)(lVb + (wn + 16 + m16) * WSTR + quad * 8);
            bf16x8 vn11 = *(const bf16x8*)(lVb + (wn + 16 + m16) * WSTR + 32 + quad * 8);
            // QK^T(kt)
            bf16x8 k00 = *(const bf16x8*)(lKb + (wk + m16) * WSTR + quad * 8);
            bf16x8 k01 = *(const bf16x8*)(lKb + (wk + m16) * WSTR + 32 + quad * 8);
            bf16x8 k10 = *(const bf16x8*)(lKb + (wk + 16 + m16) * WSTR + quad * 8);
            bf16x8 k11 = *(const bf16x8*)(lKb + (wk + 16 + m16) * WSTR + 32 + quad * 8);
            f32x4 sacc[2][2] = {};
            sacc[0][0] = MFMA16(k00, qf[0][0], sacc[0][0]);
            sacc[0][1] = MFMA16(k00, qf[1][0], sacc[0][1]);
            sacc[1][0] = MFMA16(k10, qf[0][0], sacc[1][0]);
            sacc[1][1] = MFMA16(k10, qf[1][0], sacc[1][1]);
            sacc[0][0] = MFMA16(k01, qf[0][1], sacc[0][0]);
            sacc[0][1] = MFMA16(k01, qf[1][1], sacc[0][1]);
            sacc[1][0] = MFMA16(k11, qf[0][1], sacc[1][0]);
            sacc[1][1] = MFMA16(k11, qf[1][1], sacc[1][1]);
            // w = exp2(s*SC)*inv (in place)
#pragma unroll
            for (int mi = 0; mi < 2; ++mi)
#pragma unroll
                for (int ni = 0; ni < 2; ++ni)
#pragma unroll
                    for (int e = 0; e < 4; ++e)
                        sacc[mi][ni][e] = __builtin_amdgcn_exp2f(sacc[mi][ni][e] * SC) * inv[ni];
            // P(kt) -> bf16 -> lW[kt&1]
            u16* lwb = &lW[(kt & 1) * TSZ];
#pragma unroll
            for (int mi = 0; mi < 2; ++mi)
#pragma unroll
                for (int ni = 0; ni < 2; ++ni) {
                    u16 p[4];
                    p[0] = cvt_bf(sacc[mi][ni][0]); p[1] = cvt_bf(sacc[mi][ni][1]);
                    p[2] = cvt_bf(sacc[mi][ni][2]); p[3] = cvt_bf(sacc[mi][ni][3]);
                    *(uint2*)&lwb[lwoff[mi][ni]] = *(const uint2*)p;
                }
            // final fp32 weights(kt) -> HBM (fire-and-forget; never drained in the loop)
            float* ap = ah + kt * 64;
#pragma unroll
            for (int mi = 0; mi < 2; ++mi)
#pragma unroll
                for (int ni = 0; ni < 2; ++ni)
                    *(f32x4*)(ap + aoff[mi][ni]) = sacc[mi][ni];
            // T14: LDS-write the staged regs (load latency covered by the work above)
            if (kt < 31) {
                u16* dK = &lK[(buf ^ 1) * TSZ];
                u16* dV = &lV[(buf ^ 1) * TSZ];
                *(uint4*)&dK[sr * WSTR + sc]        = kr0;
                *(uint4*)&dK[(sr + 32) * WSTR + sc] = kr1;
                *(uint4*)&dV[sr * WSTR + sc]        = vr0;
                *(uint4*)&dV[(sr + 32) * WSTR + sc] = vr1;
            }
            // PV(kt-1): lW[(kt-1)&1] (visible via this kt's barrier) x V(kt-1) (registers)
            if (kt > 0) {
                const u16* lwp = &lW[((kt - 1) & 1) * TSZ];
                bf16x8 a00 = *(const bf16x8*)(lwp + (wm + m16) * WSTR + quad * 8);
                bf16x8 a01 = *(const bf16x8*)(lwp + (wm + m16) * WSTR + 32 + quad * 8);
                bf16x8 a10 = *(const bf16x8*)(lwp + (wm + 16 + m16) * WSTR + quad * 8);
                bf16x8 a11 = *(const bf16x8*)(lwp + (wm + 16 + m16) * WSTR + 32 + quad * 8);
                cacc[0][0] = MFMA16(a00, vp00, cacc[0][0]);
                cacc[0][1] = MFMA16(a00, vp10, cacc[0][1]);
                cacc[1][0] = MFMA16(a10, vp00, cacc[1][0]);
                cacc[1][1] = MFMA16(a10, vp10, cacc[1][1]);
                cacc[0][0] = MFMA16(a01, vp01, cacc[0][0]);
                cacc[0][1] = MFMA16(a01, vp11, cacc[0][1]);
                cacc[1][0] = MFMA16(a11, vp01, cacc[1][0]);
                cacc[1][1] = MFMA16(a11, vp11, cacc[1][1]);
            }
            vp00 = vn00; vp01 = vn01; vp10 = vn10; vp11 = vn11;
            buf ^= 1;
        }
        // drain: PV(31)
        __syncthreads();
        const u16* lwp = &lW[(31 & 1) * TSZ];
        bf16x8 a00 = *(const bf16x8*)(lwp + (wm + m16) * WSTR + quad * 8);
        bf16x8 a01 = *(const bf16x8*)(lwp + (wm + m16) * WSTR + 32 + quad * 8);
        bf16x8 a10 = *(const bf16x8*)(lwp + (wm + 16 + m16) * WSTR + quad * 8);
        bf16x8 a11 = *(const bf16x8*)(lwp + (wm + 16 + m16) * WSTR + 32 + quad * 8);
        cacc[0][0] = MFMA16(a00, vp00, cacc[0][0]);
        cacc[0][1] = MFMA16(a00, vp10, cacc[0][1]);
        cacc[1][0] = MFMA16(a10, vp00, cacc[1][0]);
        cacc[1][1] = MFMA16(a10, vp10, cacc[1][1]);
        cacc[0][0] = MFMA16(a01, vp01, cacc[0][0]);
        cacc[0][1] = MFMA16(a01, vp11, cacc[0][1]);
        cacc[1][0] = MFMA16(a11, vp01, cacc[1][0]);
        cacc[1][1] = MFMA16(a11, vp11, cacc[1][1]);
    }

    // epilogue: ctx in plain [b*2048+l][1024] row-major (h*64+d cols)
    const int b = bh >> 4, h = bh & 15;
    u16* cp = ctx + ((size_t)b * 2048) * 1024 + h * 64;
#pragma unroll
    for (int mi = 0; mi < 2; ++mi)
#pragma unroll
        for (int ni = 0; ni < 2; ++ni)
#pragma unroll
            for (int e = 0; e < 4; ++e) {
                const int row = m0 + wm + mi * 16 + quad * 4 + e;
                const int col = wn + ni * 16 + m16;
                cp[(size_t)row * 1024 + col] = cvt_bf(cacc[mi][ni][e]);
            }
}

// ---------- 3) out = ctx @ Wo^T + bo, m97 128x128 structure; ctx is [4096][1024] bf16 ----------
__global__ __launch_bounds__(256) void k_out(const u16* __restrict__ ctx,
                                             const u16* __restrict__ WoB,
                                             const float* __restrict__ bo,
                                             float* __restrict__ out) {
    __shared__ __align__(16) u16 lA[128 * 32];
    __shared__ __align__(16) u16 lB[128 * 32];
    const int t = threadIdx.x;
    const int n0 = blockIdx.x * 128;
    const int m0 = blockIdx.y * 128;
    const int lane = t & 63, wave = t >> 6;
    const int wm = (wave >> 1) * 64, wn = (wave & 1) * 64;
    const int quad = lane >> 4, m16 = lane & 15;
    const int r4 = t >> 2, c8 = (t & 3) * 8;
    f32x4 acc[4][4] = {};
    for (int k0 = 0; k0 < 1024; k0 += 32) {
        gload16(ctx + (size_t)(m0 + r4) * 1024 + k0 + c8,       &lA[t * 8]);
        gload16(ctx + (size_t)(m0 + 64 + r4) * 1024 + k0 + c8,  &lA[2048 + t * 8]);
        gload16(WoB + (size_t)(n0 + r4) * 1024 + k0 + c8,       &lB[t * 8]);
        gload16(WoB + (size_t)(n0 + 64 + r4) * 1024 + k0 + c8,  &lB[2048 + t * 8]);
        __syncthreads();
        bf16x8 af[4], bfr[4];
#pragma unroll
        for (int i = 0; i < 4; ++i) {
            af[i]  = *(const bf16x8*)(lA + (wm + i * 16 + m16) * 32 + quad * 8);
            bfr[i] = *(const bf16x8*)(lB + (wn + i * 16 + m16) * 32 + quad * 8);
        }
#pragma unroll
        for (int mi = 0; mi < 4; ++mi)
#pragma unroll
            for (int ni = 0; ni < 4; ++ni)
                acc[mi][ni] = MFMA16(af[mi], bfr[ni], acc[mi][ni]);
        __syncthreads();
    }
#pragma unroll
    for (int ni = 0; ni < 4; ++ni) {
        const int col = n0 + wn + ni * 16 + m16;
        const float bv = bo[col];
#pragma unroll
        for (int mi = 0; mi < 4; ++mi)
#pragma unroll
            for (int e = 0; e < 4; ++e) {
                const int row = m0 + wm + mi * 16 + quad * 4 + e;
                out[(size_t)row * 1024 + col] = acc[mi][ni][e] + bv;
            }
    }
}

extern "C" void kernel_launch(void* const* d_in, const int* in_sizes, int n_in,
                              void* d_out, int out_size, void* d_ws, size_t ws_size,
                              hipStream_t stream) {
    const float* x  = (const float*)d_in[0];
    const float* Wq = (const float*)d_in[1];
    const float* bq = (const float*)d_in[2];
    const float* Wk = (const float*)d_in[3];
    const float* bk = (const float*)d_in[4];
    const float* Wv = (const float*)d_in[5];
    const float* bv = (const float*)d_in[6];
    const float* Wo = (const float*)d_in[7];
    const float* bo = (const float*)d_in[8];

    float* out_f = (float*)d_out;
    float* attn  = out_f + (size_t)4096 * 1024;  // [2,16,2048,2048]

    u16* Xb = (u16*)d_ws;                        // X bf16 [4096][1024]; reused as ctx after k_qkv
    u16* Wb = Xb + (size_t)4194304;              // Wq|Wk|Wv|Wo bf16 stacked [4096][1024]
    u16* Qb = Wb + (size_t)4194304;
    u16* Kb = Qb + (size_t)4194304;
    u16* Vt = Kb + (size_t)4194304;              // V transposed [b,h,d,l]
    u16* Vtmp = (u16*)attn;                      // V [bh][l][d] scratch inside attn region (dead until k_attn)

    dim3 blk(256);
    k_cvtX<<<dim3(2048), blk, 0, stream>>>(x, Xb);
    k_cvtW<<<dim3(512, 1, 4), blk, 0, stream>>>(Wq, Wk, Wv, Wo, Wb);
    k_qkv<<<dim3(24, 32), blk, 0, stream>>>(Xb, Wb, bq, bk, bv, Qb, Kb, Vtmp);
    k_vtr<<<dim3(32, 32), blk, 0, stream>>>(Vtmp, Vt);
    k_attn<<<dim3(32, 32), blk, 0, stream>>>(Qb, Kb, Vt, attn, Xb);  // ctx -> Xb
    k_out<<<dim3(8, 32), blk, 0, stream>>>(Xb, Wb + (size_t)3072 * 1024, bo, out_f);
}